// Round 11
// baseline (235.604 us; speedup 1.0000x reference)
//
#include <hip/hip_runtime.h>

#define HID 64
#define DIN 128
#define NBLK 256                // blocks for hist/scatter passes

typedef unsigned long long ull;
typedef unsigned short u16;

static __device__ __forceinline__ u16 f2bf(float f) {
  unsigned u = __float_as_uint(f);
  unsigned lsb = (u >> 16) & 1u;
  u += 0x7fffu + lsb;
  return (u16)(u >> 16);
}

// ============ K1: coarse histogram (bucket = dst>>8) -> G[t][b] raw counts ============
// Trailing blocks (b >= NBLK) do the weight transposes (fused launch).

__global__ __launch_bounds__(512) void k_histA(const int* __restrict__ dst,
                                               int* __restrict__ G,
                                               int E, int NBC, int chunk,
                                               const float* __restrict__ W1,
                                               const float* __restrict__ W2,
                                               float* __restrict__ WT1,
                                               float* __restrict__ WT2) {
  int b = blockIdx.x, tid = threadIdx.x;
  if (b >= NBLK) {               // weight-transpose tail blocks
    int idx = (b - NBLK) * 512 + tid;
    if (idx < DIN * 64) {
      int d = idx >> 6, j = idx & 63;
      WT1[idx] = W1[j * DIN + d];
    }
    int i2 = idx - DIN * 64;
    if (i2 >= 0 && i2 < HID * 64) {
      int d = i2 >> 6, j = i2 & 63;
      WT2[i2] = W2[j * HID + d];
    }
    return;
  }
  __shared__ int h[256];
  if (tid < 256) h[tid] = 0;
  __syncthreads();
  int e0 = b * chunk, e1 = min(E, e0 + chunk);
  for (int e = e0 + tid; e < e1; e += 512) atomicAdd(&h[dst[e] >> 8], 1);
  __syncthreads();
  if (tid < NBC) G[tid * NBLK + b] = h[tid];   // bin-major raw counts (no scan!)
}

// ============ K2: bucket totals + 256-scan -> base[], cursor[] (one block) ============

__global__ __launch_bounds__(1024) void k_scan196(const int* __restrict__ G,
                                                  int* __restrict__ base,
                                                  int* __restrict__ cursor,
                                                  int NBC, int E) {
  __shared__ int tot[256];
  int tid = threadIdx.x;
  int w = tid >> 6, lane = tid & 63;
  if (tid < 256) tot[tid] = 0;
  __syncthreads();
  for (int t = w; t < NBC; t += 16) {           // wave w sums bucket t's 256 counts
    int s = 0;
    for (int b = lane; b < NBLK; b += 64) s += G[t * NBLK + b];
    for (int o = 32; o > 0; o >>= 1) s += __shfl_down(s, o);
    if (lane == 0) tot[t] = s;
  }
  __syncthreads();
  int own = (tid < 256) ? tot[tid] : 0;
  // inclusive Hillis-Steele scan over 256 bins
  for (int o = 1; o < 256; o <<= 1) {
    int u = 0;
    if (tid < 256 && tid >= o) u = tot[tid - o];
    __syncthreads();
    if (tid < 256) tot[tid] += u;
    __syncthreads();
  }
  if (tid < 256) {
    int excl = tot[tid] - own;
    base[tid] = excl;
    cursor[tid] = excl;
  }
  if (tid == 0) base[256] = E;                  // also base[t>=NBC] == E via tot=0
}

// ============ K3: scatter into coarse buckets; dynamic per-(block,bucket) reservation ============
// record int2 = ( float_bits(ew), (src<<16)|dst )

__global__ __launch_bounds__(512) void k_scatterA(const int* __restrict__ src,
                                                  const int* __restrict__ dst,
                                                  const float* __restrict__ ew,
                                                  const int* __restrict__ G,
                                                  int* __restrict__ cursor,
                                                  int2* __restrict__ bufA,
                                                  int E, int NBC, int chunk) {
  __shared__ int cur[256];
  int b = blockIdx.x, tid = threadIdx.x;
  if (tid < NBC) {
    int myh = G[tid * NBLK + b];                // this block's count for bucket tid
    cur[tid] = atomicAdd(&cursor[tid], myh);    // reserve a run (any order is fine)
  }
  __syncthreads();
  int e0 = b * chunk, e1 = min(E, e0 + chunk);
  for (int e = e0 + tid; e < e1; e += 512) {
    int s = src[e], d = dst[e];
    float w = ew[e];
    int p = atomicAdd(&cur[d >> 8], 1);
    bufA[p] = make_int2(__float_as_int(w), (int)(((unsigned)s << 16) | (unsigned)d));
  }
}

// ============ K4: one block per coarse bucket -> dst-grouped + offs + dinv ============

__global__ __launch_bounds__(512) void k_passB(const int2* __restrict__ bufA,
                                               const int* __restrict__ base,
                                               int2* __restrict__ bufB,
                                               int* __restrict__ offs,
                                               float* __restrict__ dinv,
                                               int NBC, int E, int N) {
  int bin = blockIdx.x, tid = threadIdx.x;
  __shared__ int h2[256];
  __shared__ int cur[256];
  __shared__ float dg[256];
  int bbase = base[bin];
  int bend  = base[bin + 1];
  int m = bend - bbase;
  if (tid < 256) { h2[tid] = 0; dg[tid] = 0.f; }
  __syncthreads();
  // phase 1: fine histogram of dst&255
  for (int i = tid; i < m; i += 512) {
    unsigned sd = (unsigned)bufA[bbase + i].y;
    atomicAdd(&h2[sd & 255], 1);
  }
  __syncthreads();
  int own = (tid < 256) ? h2[tid] : 0;
  // inclusive Hillis-Steele scan over 256 bins
  for (int o = 1; o < 256; o <<= 1) {
    int u = 0;
    if (tid < 256 && tid >= o) u = h2[tid - o];
    __syncthreads();
    if (tid < 256) h2[tid] += u;
    __syncthreads();
  }
  int nd = (bin << 8) + tid;
  if (tid < 256) {
    int excl = h2[tid] - own;
    cur[tid] = excl;
    if (nd < N) offs[nd] = bbase + excl;
  }
  if (bin == NBC - 1 && tid == 0) offs[N] = E;
  __syncthreads();
  // phase 2: scatter into dst-grouped order + weighted degree
  for (int i = tid; i < m; i += 512) {
    int2 r = bufA[bbase + i];
    unsigned sd = (unsigned)r.y;
    int dl = (int)(sd & 255u);
    int p = atomicAdd(&cur[dl], 1);
    bufB[bbase + p] = r;
    atomicAdd(&dg[dl], __int_as_float(r.x));
  }
  __syncthreads();
  if (tid < 256 && nd < N) dinv[nd] = rsqrtf(1.0f + dg[tid]);  // self-loop w=1; deg>=1
}

// ============ K5: GEMM (bf16 out) + fused norm prepass in tail blocks ============
// W pre-transposed (WTg[d][j]); conflict-free float4 LDS staging; inner loop
// 4-wide in d. Tail blocks (>= gblk) rewrite records (ew, src|dst)->(norm, src).

template <int K>
__global__ __launch_bounds__(256) void k_gemm(const float* __restrict__ X,
                                              const float* __restrict__ WTg,
                                              u16* __restrict__ out, int n_nodes,
                                              int2* __restrict__ recs,
                                              const float* __restrict__ dinv,
                                              int E, int gblk) {
  const int tid = threadIdx.x;
  if ((int)blockIdx.x >= gblk) {               // fused norm tail
    int nb = gridDim.x - gblk;
    for (int e = ((int)blockIdx.x - gblk) * 256 + tid; e < E; e += nb * 256) {
      int2 r = recs[e];
      unsigned sd = (unsigned)r.y;
      int s = (int)(sd >> 16), d = (int)(sd & 0xffffu);
      float nrm = dinv[s] * __int_as_float(r.x) * dinv[d];
      recs[e] = make_int2(__float_as_int(nrm), s);
    }
    return;
  }
  constexpr int PAD = 68;                 // float4-aligned row stride
  __shared__ float XT[64 * PAD];          // XT[m][d]  (row-major)
  __shared__ float WL[64 * PAD];          // WL[d][j]
  const int n0 = blockIdx.x * 64;
  const int tx = tid & 15;                // feature group: j = 4*tx + ji
  const int ty = tid >> 4;                // node group:    m = 4*ty + mi
  float acc[4][4] = {{0.f}};

  for (int ph = 0; ph < K / 64; ++ph) {
    const int d0 = ph * 64;
    __syncthreads();
#pragma unroll
    for (int k = 0; k < 4; ++k) {
      int f = tid + k * 256;              // 0..1023 float4 slots per tile
      int r = f >> 4, q = f & 15;         // r = row, q = float4 column
      int n = n0 + r;
      float4 xv = (n < n_nodes)
        ? *reinterpret_cast<const float4*>(&X[(size_t)n * K + d0 + 4 * q])
        : make_float4(0.f, 0.f, 0.f, 0.f);
      *reinterpret_cast<float4*>(&XT[r * PAD + 4 * q]) = xv;
      float4 wv = *reinterpret_cast<const float4*>(&WTg[(size_t)(d0 + r) * 64 + 4 * q]);
      *reinterpret_cast<float4*>(&WL[r * PAD + 4 * q]) = wv;
    }
    __syncthreads();
#pragma unroll 4
    for (int dd = 0; dd < 64; dd += 4) {
      float4 xs[4], ws[4];
#pragma unroll
      for (int mi = 0; mi < 4; ++mi)
        xs[mi] = *reinterpret_cast<const float4*>(&XT[(4 * ty + mi) * PAD + dd]);
#pragma unroll
      for (int dk = 0; dk < 4; ++dk)
        ws[dk] = *reinterpret_cast<const float4*>(&WL[(dd + dk) * PAD + 4 * tx]);
#pragma unroll
      for (int mi = 0; mi < 4; ++mi) {
        float xm[4] = {xs[mi].x, xs[mi].y, xs[mi].z, xs[mi].w};
#pragma unroll
        for (int dk = 0; dk < 4; ++dk) {
          acc[mi][0] = fmaf(xm[dk], ws[dk].x, acc[mi][0]);
          acc[mi][1] = fmaf(xm[dk], ws[dk].y, acc[mi][1]);
          acc[mi][2] = fmaf(xm[dk], ws[dk].z, acc[mi][2]);
          acc[mi][3] = fmaf(xm[dk], ws[dk].w, acc[mi][3]);
        }
      }
    }
  }

#pragma unroll
  for (int mi = 0; mi < 4; ++mi) {
    int n = n0 + 4 * ty + mi;
    if (n < n_nodes) {
      ushort4 o = make_ushort4(f2bf(acc[mi][0]), f2bf(acc[mi][1]),
                               f2bf(acc[mi][2]), f2bf(acc[mi][3]));
      *reinterpret_cast<ushort4*>(&out[(size_t)n * HID + 4 * tx]) = o;
    }
  }
}

// ============ aggregation v6: eighth-wave per node ============
// Wave = 8 independent 8-lane groups; group g owns one node fully: 8 lanes x
// 8 feats via one 16B (uint4 = 8x bf16) load -> 8 edges per wave-instruction.
// Unroll-8 main loop: 8 gathers in flight per group (64 lines/wave).
// mode 0: out = relu(agg + bias)          (layer 1 -> h1, fp32)
// mode 1: out = agg + bias + resid        (layer 2 -> final, fp32)

__device__ __forceinline__ void bfma8(const uint4& v, float w, float* a) {
  a[0] = fmaf(__uint_as_float(v.x << 16), w, a[0]);
  a[1] = fmaf(__uint_as_float(v.x & 0xffff0000u), w, a[1]);
  a[2] = fmaf(__uint_as_float(v.y << 16), w, a[2]);
  a[3] = fmaf(__uint_as_float(v.y & 0xffff0000u), w, a[3]);
  a[4] = fmaf(__uint_as_float(v.z << 16), w, a[4]);
  a[5] = fmaf(__uint_as_float(v.z & 0xffff0000u), w, a[5]);
  a[6] = fmaf(__uint_as_float(v.w << 16), w, a[6]);
  a[7] = fmaf(__uint_as_float(v.w & 0xffff0000u), w, a[7]);
}

__global__ __launch_bounds__(256) void k_agg(const u16* __restrict__ h,
                                             const int2* __restrict__ recs,
                                             const int* __restrict__ offs,
                                             const float* __restrict__ dinv,
                                             const float* __restrict__ bias,
                                             const float* __restrict__ resid,
                                             float* __restrict__ out, int n_nodes, int mode) {
  int tid = threadIdx.x;
  int lane = tid & 63;
  int g = lane >> 3;                  // group 0..7
  int p8 = (lane & 7) * 8;            // feature base (8 feats per lane)
  int node = (blockIdx.x * 4 + (tid >> 6)) * 8 + g;   // 32 nodes per block
  if (node >= n_nodes) return;
  int beg = offs[node], end = offs[node + 1];
  float di = dinv[node];

  float a[8], b[8];
  {
    uint4 v = *reinterpret_cast<const uint4*>(&h[(size_t)node * HID + p8]);
    float w = di * di;                // self loop (weight 1.0)
    a[0] = __uint_as_float(v.x << 16) * w;
    a[1] = __uint_as_float(v.x & 0xffff0000u) * w;
    a[2] = __uint_as_float(v.y << 16) * w;
    a[3] = __uint_as_float(v.y & 0xffff0000u) * w;
    a[4] = __uint_as_float(v.z << 16) * w;
    a[5] = __uint_as_float(v.z & 0xffff0000u) * w;
    a[6] = __uint_as_float(v.w << 16) * w;
    a[7] = __uint_as_float(v.w & 0xffff0000u) * w;
#pragma unroll
    for (int j = 0; j < 8; ++j) b[j] = 0.f;
  }

  int i = beg;
  while (i + 8 <= end) {              // 8 gathers in flight per group
    int2 r0 = recs[i];     int2 r1 = recs[i + 1];
    int2 r2 = recs[i + 2]; int2 r3 = recs[i + 3];
    int2 r4 = recs[i + 4]; int2 r5 = recs[i + 5];
    int2 r6 = recs[i + 6]; int2 r7 = recs[i + 7];
    uint4 v0 = *reinterpret_cast<const uint4*>(&h[(size_t)r0.y * HID + p8]);
    uint4 v1 = *reinterpret_cast<const uint4*>(&h[(size_t)r1.y * HID + p8]);
    uint4 v2 = *reinterpret_cast<const uint4*>(&h[(size_t)r2.y * HID + p8]);
    uint4 v3 = *reinterpret_cast<const uint4*>(&h[(size_t)r3.y * HID + p8]);
    uint4 v4 = *reinterpret_cast<const uint4*>(&h[(size_t)r4.y * HID + p8]);
    uint4 v5 = *reinterpret_cast<const uint4*>(&h[(size_t)r5.y * HID + p8]);
    uint4 v6 = *reinterpret_cast<const uint4*>(&h[(size_t)r6.y * HID + p8]);
    uint4 v7 = *reinterpret_cast<const uint4*>(&h[(size_t)r7.y * HID + p8]);
    bfma8(v0, __int_as_float(r0.x), a);
    bfma8(v1, __int_as_float(r1.x), b);
    bfma8(v2, __int_as_float(r2.x), a);
    bfma8(v3, __int_as_float(r3.x), b);
    bfma8(v4, __int_as_float(r4.x), a);
    bfma8(v5, __int_as_float(r5.x), b);
    bfma8(v6, __int_as_float(r6.x), a);
    bfma8(v7, __int_as_float(r7.x), b);
    i += 8;
  }
  if (i + 4 <= end) {
    int2 r0 = recs[i];     int2 r1 = recs[i + 1];
    int2 r2 = recs[i + 2]; int2 r3 = recs[i + 3];
    uint4 v0 = *reinterpret_cast<const uint4*>(&h[(size_t)r0.y * HID + p8]);
    uint4 v1 = *reinterpret_cast<const uint4*>(&h[(size_t)r1.y * HID + p8]);
    uint4 v2 = *reinterpret_cast<const uint4*>(&h[(size_t)r2.y * HID + p8]);
    uint4 v3 = *reinterpret_cast<const uint4*>(&h[(size_t)r3.y * HID + p8]);
    bfma8(v0, __int_as_float(r0.x), a);
    bfma8(v1, __int_as_float(r1.x), b);
    bfma8(v2, __int_as_float(r2.x), a);
    bfma8(v3, __int_as_float(r3.x), b);
    i += 4;
  }
  if (i + 2 <= end) {
    int2 r0 = recs[i];     int2 r1 = recs[i + 1];
    uint4 v0 = *reinterpret_cast<const uint4*>(&h[(size_t)r0.y * HID + p8]);
    uint4 v1 = *reinterpret_cast<const uint4*>(&h[(size_t)r1.y * HID + p8]);
    bfma8(v0, __int_as_float(r0.x), a);
    bfma8(v1, __int_as_float(r1.x), b);
    i += 2;
  }
  if (i < end) {
    int2 r0 = recs[i];
    uint4 v0 = *reinterpret_cast<const uint4*>(&h[(size_t)r0.y * HID + p8]);
    bfma8(v0, __int_as_float(r0.x), a);
  }

  float r[8];
#pragma unroll
  for (int j = 0; j < 8; ++j) r[j] = a[j] + b[j];
  float4 bb0 = *reinterpret_cast<const float4*>(&bias[p8]);
  float4 bb1 = *reinterpret_cast<const float4*>(&bias[p8 + 4]);
  r[0] += bb0.x; r[1] += bb0.y; r[2] += bb0.z; r[3] += bb0.w;
  r[4] += bb1.x; r[5] += bb1.y; r[6] += bb1.z; r[7] += bb1.w;
  if (mode == 0) {
#pragma unroll
    for (int j = 0; j < 8; ++j) r[j] = fmaxf(r[j], 0.f);
  } else {
    float4 rs0 = *reinterpret_cast<const float4*>(&resid[(size_t)node * HID + p8]);
    float4 rs1 = *reinterpret_cast<const float4*>(&resid[(size_t)node * HID + p8 + 4]);
    r[0] += rs0.x; r[1] += rs0.y; r[2] += rs0.z; r[3] += rs0.w;
    r[4] += rs1.x; r[5] += rs1.y; r[6] += rs1.z; r[7] += rs1.w;
  }
  *reinterpret_cast<float4*>(&out[(size_t)node * HID + p8]) =
      make_float4(r[0], r[1], r[2], r[3]);
  *reinterpret_cast<float4*>(&out[(size_t)node * HID + p8 + 4]) =
      make_float4(r[4], r[5], r[6], r[7]);
}

// ============ launcher (8 dispatches) ============

extern "C" void kernel_launch(void* const* d_in, const int* in_sizes, int n_in,
                              void* d_out, int out_size, void* d_ws, size_t ws_size,
                              hipStream_t stream) {
  const float* x  = (const float*)d_in[0];
  const int*   ei = (const int*)d_in[1];
  const float* ew = (const float*)d_in[2];
  const float* W1 = (const float*)d_in[3];
  const float* b1 = (const float*)d_in[4];
  const float* W2 = (const float*)d_in[5];
  const float* b2 = (const float*)d_in[6];
  float* out = (float*)d_out;

  const int N = in_sizes[0] / DIN;
  const int E = in_sizes[2];
  const int* src = ei;        // ei shape (2,E) row-major
  const int* dst = ei + E;

  const int NBC = (N + 255) >> 8;          // coarse buckets (196 for N=50000)
  const int chunk = (E + NBLK - 1) / NBLK;

  char* p = (char*)d_ws;
  auto carve = [&](size_t bytes) {
    char* r = p;
    p += (bytes + 255) & ~(size_t)255;
    return r;
  };
  int*   G      = (int*)carve((size_t)256 * NBLK * 4);
  int*   base   = (int*)carve(257 * 4);
  int*   cursor = (int*)carve(256 * 4);
  int*   offs   = (int*)carve((size_t)(N + 1) * 4);
  float* dinv   = (float*)carve((size_t)N * 4);
  int2*  bufA   = (int2*)carve((size_t)E * 8);
  int2*  bufB   = (int2*)carve((size_t)E * 8);
  u16*   h      = (u16*)carve((size_t)N * HID * 2);   // bf16 linear outputs (gathered)
  float* h1     = (float*)carve((size_t)N * HID * 4); // fp32 layer-1 activations
  float* WT1    = (float*)carve((size_t)DIN * HID * 4);
  float* WT2    = (float*)carve((size_t)HID * HID * 4);

  int gblk = (N + 63) / 64;
  int ablk = (N + 31) / 32;                   // 32 nodes per 256-thread block
  int tblk = ((DIN + HID) * 64 + 511) / 512;  // transpose tail blocks
  int nblk = (E + 1023) / 1024;               // norm tail blocks (4 edges/thread)

  // ---- build: 4 dispatches, zero scans over E-sized arrays beyond the sort itself ----
  k_histA<<<NBLK + tblk, 512, 0, stream>>>(dst, G, E, NBC, chunk, W1, W2, WT1, WT2);
  k_scan196<<<1, 1024, 0, stream>>>(G, base, cursor, NBC, E);
  k_scatterA<<<NBLK, 512, 0, stream>>>(src, dst, ew, G, cursor, bufA, E, NBC, chunk);
  k_passB<<<NBC, 512, 0, stream>>>(bufA, base, bufB, offs, dinv, NBC, E, N);

  // ---- layer 1 (norm prepass fused into gemm1's tail blocks) ----
  k_gemm<DIN><<<gblk + nblk, 256, 0, stream>>>(x, WT1, h, N, bufB, dinv, E, gblk);
  k_agg<<<ablk, 256, 0, stream>>>(h, bufB, offs, dinv, b1, nullptr, h1, N, 0);
  // ---- layer 2 ----
  k_gemm<HID><<<gblk, 256, 0, stream>>>(h1, WT2, h, N, nullptr, nullptr, 0, gblk);
  k_agg<<<ablk, 256, 0, stream>>>(h, bufB, offs, dinv, b2, h1, out, N, 1);
}

// Round 12
// 226.717 us; speedup vs baseline: 1.0392x; 1.0392x over previous
//
#include <hip/hip_runtime.h>

#define HID 64
#define DIN 128
#define NBLK 512                // blocks for the build pass
#define CSH 14                  // slab capacity shift: 16384 entries per bucket
#define CAP (1 << CSH)

typedef unsigned long long ull;
typedef unsigned short u16;

static __device__ __forceinline__ u16 f2bf(float f) {
  unsigned u = __float_as_uint(f);
  unsigned lsb = (u >> 16) & 1u;
  u += 0x7fffu + lsb;
  return (u16)(u >> 16);
}

// ============ K1: fused build — LDS hist + slab reservation + scatter ============
// record int2 = ( float_bits(ew), (src<<16)|dst ). Bucket t's slab = [t<<CSH, ...).
// Trailing blocks (b >= NBLK) do the weight transposes (fused launch).

__global__ __launch_bounds__(512) void k_build(const int* __restrict__ src,
                                               const int* __restrict__ dst,
                                               const float* __restrict__ ew,
                                               int* __restrict__ cursor,
                                               int2* __restrict__ bufA,
                                               int E, int NBC, int chunk,
                                               const float* __restrict__ W1,
                                               const float* __restrict__ W2,
                                               float* __restrict__ WT1,
                                               float* __restrict__ WT2) {
  int b = blockIdx.x, tid = threadIdx.x;
  if (b >= NBLK) {               // weight-transpose tail blocks
    int idx = (b - NBLK) * 512 + tid;
    if (idx < DIN * 64) {
      int d = idx >> 6, j = idx & 63;
      WT1[idx] = W1[j * DIN + d];
    }
    int i2 = idx - DIN * 64;
    if (i2 >= 0 && i2 < HID * 64) {
      int d = i2 >> 6, j = i2 & 63;
      WT2[i2] = W2[j * HID + d];
    }
    return;
  }
  __shared__ int h[256];
  __shared__ int cur[256];
  if (tid < 256) h[tid] = 0;
  __syncthreads();
  int e0 = b * chunk, e1 = min(E, e0 + chunk);
  // pass 1: LDS histogram of this chunk
  for (int e = e0 + tid; e < e1; e += 512) atomicAdd(&h[dst[e] >> 8], 1);
  __syncthreads();
  // reserve a contiguous run in each bucket's slab
  if (tid < 256) {
    int c = h[tid];
    int ofs = (c > 0) ? atomicAdd(&cursor[tid], c) : 0;
    cur[tid] = (tid << CSH) + ofs;
  }
  __syncthreads();
  // pass 2: scatter records
  for (int e = e0 + tid; e < e1; e += 512) {
    int s = src[e], d = dst[e];
    float w = ew[e];
    int p = atomicAdd(&cur[d >> 8], 1);
    bufA[p] = make_int2(__float_as_int(w), (int)(((unsigned)s << 16) | (unsigned)d));
  }
}

// ============ K2: one block per coarse bucket -> dst-grouped + offs/cnt + dinv ============

__global__ __launch_bounds__(512) void k_passB(const int2* __restrict__ bufA,
                                               const int* __restrict__ cursor,
                                               int2* __restrict__ bufB,
                                               int* __restrict__ offs,
                                               int* __restrict__ cnt,
                                               float* __restrict__ dinv,
                                               int NBC, int N) {
  int bin = blockIdx.x, tid = threadIdx.x;
  __shared__ int h2[256];
  __shared__ int cur[256];
  __shared__ float dg[256];
  int bbase = bin << CSH;
  int m = cursor[bin];
  if (tid < 256) { h2[tid] = 0; dg[tid] = 0.f; }
  __syncthreads();
  // phase 1: fine histogram of dst&255
  for (int i = tid; i < m; i += 512) {
    unsigned sd = (unsigned)bufA[bbase + i].y;
    atomicAdd(&h2[sd & 255], 1);
  }
  __syncthreads();
  int own = (tid < 256) ? h2[tid] : 0;
  // inclusive Hillis-Steele scan over 256 bins
  for (int o = 1; o < 256; o <<= 1) {
    int u = 0;
    if (tid < 256 && tid >= o) u = h2[tid - o];
    __syncthreads();
    if (tid < 256) h2[tid] += u;
    __syncthreads();
  }
  int nd = (bin << 8) + tid;
  if (tid < 256) {
    int excl = h2[tid] - own;
    cur[tid] = excl;
    if (nd < N) { offs[nd] = bbase + excl; cnt[nd] = own; }
  }
  __syncthreads();
  // phase 2: scatter into dst-grouped order + weighted degree
  for (int i = tid; i < m; i += 512) {
    int2 r = bufA[bbase + i];
    unsigned sd = (unsigned)r.y;
    int dl = (int)(sd & 255u);
    int p = atomicAdd(&cur[dl], 1);
    bufB[bbase + p] = r;
    atomicAdd(&dg[dl], __int_as_float(r.x));
  }
  __syncthreads();
  if (tid < 256 && nd < N) dinv[nd] = rsqrtf(1.0f + dg[tid]);  // self-loop w=1; deg>=1
}

// ============ K3: norm prepass over slabs: (ew, src|dst) -> (norm, src) ============
// Gap entries (rel >= count) are skipped.

__global__ __launch_bounds__(256) void k_norm(int2* __restrict__ recs,
                                              const int* __restrict__ cursor,
                                              const float* __restrict__ dinv, int nslab) {
  int e = blockIdx.x * 256 + threadIdx.x;
  if (e < nslab && (e & (CAP - 1)) < cursor[e >> CSH]) {
    int2 r = recs[e];
    unsigned sd = (unsigned)r.y;
    int s = (int)(sd >> 16), d = (int)(sd & 0xffffu);
    float nrm = dinv[s] * __int_as_float(r.x) * dinv[d];
    recs[e] = make_int2(__float_as_int(nrm), s);
  }
}

// ============ K4: GEMM: out[N][64] = X[N][K] @ W[64][K]^T, bf16 output ============
// W pre-transposed (WTg[d][j]); conflict-free float4 LDS staging; inner loop
// 4-wide in d: 8 b128 LDS reads per 64 FMAs -> VALU-bound.

template <int K>
__global__ __launch_bounds__(256) void k_gemm(const float* __restrict__ X,
                                              const float* __restrict__ WTg,
                                              u16* __restrict__ out, int n_nodes) {
  constexpr int PAD = 68;                 // float4-aligned row stride
  __shared__ float XT[64 * PAD];          // XT[m][d]  (row-major)
  __shared__ float WL[64 * PAD];          // WL[d][j]
  const int tid = threadIdx.x;
  const int n0 = blockIdx.x * 64;
  const int tx = tid & 15;                // feature group: j = 4*tx + ji
  const int ty = tid >> 4;                // node group:    m = 4*ty + mi
  float acc[4][4] = {{0.f}};

  for (int ph = 0; ph < K / 64; ++ph) {
    const int d0 = ph * 64;
    __syncthreads();
#pragma unroll
    for (int k = 0; k < 4; ++k) {
      int f = tid + k * 256;              // 0..1023 float4 slots per tile
      int r = f >> 4, q = f & 15;         // r = row, q = float4 column
      int n = n0 + r;
      float4 xv = (n < n_nodes)
        ? *reinterpret_cast<const float4*>(&X[(size_t)n * K + d0 + 4 * q])
        : make_float4(0.f, 0.f, 0.f, 0.f);
      *reinterpret_cast<float4*>(&XT[r * PAD + 4 * q]) = xv;
      float4 wv = *reinterpret_cast<const float4*>(&WTg[(size_t)(d0 + r) * 64 + 4 * q]);
      *reinterpret_cast<float4*>(&WL[r * PAD + 4 * q]) = wv;
    }
    __syncthreads();
#pragma unroll 4
    for (int dd = 0; dd < 64; dd += 4) {
      float4 xs[4], ws[4];
#pragma unroll
      for (int mi = 0; mi < 4; ++mi)
        xs[mi] = *reinterpret_cast<const float4*>(&XT[(4 * ty + mi) * PAD + dd]);
#pragma unroll
      for (int dk = 0; dk < 4; ++dk)
        ws[dk] = *reinterpret_cast<const float4*>(&WL[(dd + dk) * PAD + 4 * tx]);
#pragma unroll
      for (int mi = 0; mi < 4; ++mi) {
        float xm[4] = {xs[mi].x, xs[mi].y, xs[mi].z, xs[mi].w};
#pragma unroll
        for (int dk = 0; dk < 4; ++dk) {
          acc[mi][0] = fmaf(xm[dk], ws[dk].x, acc[mi][0]);
          acc[mi][1] = fmaf(xm[dk], ws[dk].y, acc[mi][1]);
          acc[mi][2] = fmaf(xm[dk], ws[dk].z, acc[mi][2]);
          acc[mi][3] = fmaf(xm[dk], ws[dk].w, acc[mi][3]);
        }
      }
    }
  }

#pragma unroll
  for (int mi = 0; mi < 4; ++mi) {
    int n = n0 + 4 * ty + mi;
    if (n < n_nodes) {
      ushort4 o = make_ushort4(f2bf(acc[mi][0]), f2bf(acc[mi][1]),
                               f2bf(acc[mi][2]), f2bf(acc[mi][3]));
      *reinterpret_cast<ushort4*>(&out[(size_t)n * HID + 4 * tx]) = o;
    }
  }
}

// ============ K5: aggregation v6 — eighth-wave per node ============
// Wave = 8 independent 8-lane groups; group g owns one node fully: 8 lanes x
// 8 feats via one 16B (uint4 = 8x bf16) load -> 8 edges per wave-instruction.
// Unroll-8 main loop: 8 gathers in flight per group (64 lines/wave).
// mode 0: out = relu(agg + bias)          (layer 1 -> h1, fp32)
// mode 1: out = agg + bias + resid        (layer 2 -> final, fp32)

__device__ __forceinline__ void bfma8(const uint4& v, float w, float* a) {
  a[0] = fmaf(__uint_as_float(v.x << 16), w, a[0]);
  a[1] = fmaf(__uint_as_float(v.x & 0xffff0000u), w, a[1]);
  a[2] = fmaf(__uint_as_float(v.y << 16), w, a[2]);
  a[3] = fmaf(__uint_as_float(v.y & 0xffff0000u), w, a[3]);
  a[4] = fmaf(__uint_as_float(v.z << 16), w, a[4]);
  a[5] = fmaf(__uint_as_float(v.z & 0xffff0000u), w, a[5]);
  a[6] = fmaf(__uint_as_float(v.w << 16), w, a[6]);
  a[7] = fmaf(__uint_as_float(v.w & 0xffff0000u), w, a[7]);
}

__global__ __launch_bounds__(256) void k_agg(const u16* __restrict__ h,
                                             const int2* __restrict__ recs,
                                             const int* __restrict__ offs,
                                             const int* __restrict__ cnt,
                                             const float* __restrict__ dinv,
                                             const float* __restrict__ bias,
                                             const float* __restrict__ resid,
                                             float* __restrict__ out, int n_nodes, int mode) {
  int tid = threadIdx.x;
  int lane = tid & 63;
  int g = lane >> 3;                  // group 0..7
  int p8 = (lane & 7) * 8;            // feature base (8 feats per lane)
  int node = (blockIdx.x * 4 + (tid >> 6)) * 8 + g;   // 32 nodes per block
  if (node >= n_nodes) return;
  int beg = offs[node], end = beg + cnt[node];
  float di = dinv[node];

  float a[8], b[8];
  {
    uint4 v = *reinterpret_cast<const uint4*>(&h[(size_t)node * HID + p8]);
    float w = di * di;                // self loop (weight 1.0)
    a[0] = __uint_as_float(v.x << 16) * w;
    a[1] = __uint_as_float(v.x & 0xffff0000u) * w;
    a[2] = __uint_as_float(v.y << 16) * w;
    a[3] = __uint_as_float(v.y & 0xffff0000u) * w;
    a[4] = __uint_as_float(v.z << 16) * w;
    a[5] = __uint_as_float(v.z & 0xffff0000u) * w;
    a[6] = __uint_as_float(v.w << 16) * w;
    a[7] = __uint_as_float(v.w & 0xffff0000u) * w;
#pragma unroll
    for (int j = 0; j < 8; ++j) b[j] = 0.f;
  }

  int i = beg;
  while (i + 8 <= end) {              // 8 gathers in flight per group
    int2 r0 = recs[i];     int2 r1 = recs[i + 1];
    int2 r2 = recs[i + 2]; int2 r3 = recs[i + 3];
    int2 r4 = recs[i + 4]; int2 r5 = recs[i + 5];
    int2 r6 = recs[i + 6]; int2 r7 = recs[i + 7];
    uint4 v0 = *reinterpret_cast<const uint4*>(&h[(size_t)r0.y * HID + p8]);
    uint4 v1 = *reinterpret_cast<const uint4*>(&h[(size_t)r1.y * HID + p8]);
    uint4 v2 = *reinterpret_cast<const uint4*>(&h[(size_t)r2.y * HID + p8]);
    uint4 v3 = *reinterpret_cast<const uint4*>(&h[(size_t)r3.y * HID + p8]);
    uint4 v4 = *reinterpret_cast<const uint4*>(&h[(size_t)r4.y * HID + p8]);
    uint4 v5 = *reinterpret_cast<const uint4*>(&h[(size_t)r5.y * HID + p8]);
    uint4 v6 = *reinterpret_cast<const uint4*>(&h[(size_t)r6.y * HID + p8]);
    uint4 v7 = *reinterpret_cast<const uint4*>(&h[(size_t)r7.y * HID + p8]);
    bfma8(v0, __int_as_float(r0.x), a);
    bfma8(v1, __int_as_float(r1.x), b);
    bfma8(v2, __int_as_float(r2.x), a);
    bfma8(v3, __int_as_float(r3.x), b);
    bfma8(v4, __int_as_float(r4.x), a);
    bfma8(v5, __int_as_float(r5.x), b);
    bfma8(v6, __int_as_float(r6.x), a);
    bfma8(v7, __int_as_float(r7.x), b);
    i += 8;
  }
  if (i + 4 <= end) {
    int2 r0 = recs[i];     int2 r1 = recs[i + 1];
    int2 r2 = recs[i + 2]; int2 r3 = recs[i + 3];
    uint4 v0 = *reinterpret_cast<const uint4*>(&h[(size_t)r0.y * HID + p8]);
    uint4 v1 = *reinterpret_cast<const uint4*>(&h[(size_t)r1.y * HID + p8]);
    uint4 v2 = *reinterpret_cast<const uint4*>(&h[(size_t)r2.y * HID + p8]);
    uint4 v3 = *reinterpret_cast<const uint4*>(&h[(size_t)r3.y * HID + p8]);
    bfma8(v0, __int_as_float(r0.x), a);
    bfma8(v1, __int_as_float(r1.x), b);
    bfma8(v2, __int_as_float(r2.x), a);
    bfma8(v3, __int_as_float(r3.x), b);
    i += 4;
  }
  if (i + 2 <= end) {
    int2 r0 = recs[i];     int2 r1 = recs[i + 1];
    uint4 v0 = *reinterpret_cast<const uint4*>(&h[(size_t)r0.y * HID + p8]);
    uint4 v1 = *reinterpret_cast<const uint4*>(&h[(size_t)r1.y * HID + p8]);
    bfma8(v0, __int_as_float(r0.x), a);
    bfma8(v1, __int_as_float(r1.x), b);
    i += 2;
  }
  if (i < end) {
    int2 r0 = recs[i];
    uint4 v0 = *reinterpret_cast<const uint4*>(&h[(size_t)r0.y * HID + p8]);
    bfma8(v0, __int_as_float(r0.x), a);
  }

  float r[8];
#pragma unroll
  for (int j = 0; j < 8; ++j) r[j] = a[j] + b[j];
  float4 bb0 = *reinterpret_cast<const float4*>(&bias[p8]);
  float4 bb1 = *reinterpret_cast<const float4*>(&bias[p8 + 4]);
  r[0] += bb0.x; r[1] += bb0.y; r[2] += bb0.z; r[3] += bb0.w;
  r[4] += bb1.x; r[5] += bb1.y; r[6] += bb1.z; r[7] += bb1.w;
  if (mode == 0) {
#pragma unroll
    for (int j = 0; j < 8; ++j) r[j] = fmaxf(r[j], 0.f);
  } else {
    float4 rs0 = *reinterpret_cast<const float4*>(&resid[(size_t)node * HID + p8]);
    float4 rs1 = *reinterpret_cast<const float4*>(&resid[(size_t)node * HID + p8 + 4]);
    r[0] += rs0.x; r[1] += rs0.y; r[2] += rs0.z; r[3] += rs0.w;
    r[4] += rs1.x; r[5] += rs1.y; r[6] += rs1.z; r[7] += rs1.w;
  }
  *reinterpret_cast<float4*>(&out[(size_t)node * HID + p8]) =
      make_float4(r[0], r[1], r[2], r[3]);
  *reinterpret_cast<float4*>(&out[(size_t)node * HID + p8 + 4]) =
      make_float4(r[4], r[5], r[6], r[7]);
}

// ============ launcher ============

extern "C" void kernel_launch(void* const* d_in, const int* in_sizes, int n_in,
                              void* d_out, int out_size, void* d_ws, size_t ws_size,
                              hipStream_t stream) {
  const float* x  = (const float*)d_in[0];
  const int*   ei = (const int*)d_in[1];
  const float* ew = (const float*)d_in[2];
  const float* W1 = (const float*)d_in[3];
  const float* b1 = (const float*)d_in[4];
  const float* W2 = (const float*)d_in[5];
  const float* b2 = (const float*)d_in[6];
  float* out = (float*)d_out;

  const int N = in_sizes[0] / DIN;
  const int E = in_sizes[2];
  const int* src = ei;        // ei shape (2,E) row-major
  const int* dst = ei + E;

  const int NBC = (N + 255) >> 8;          // coarse buckets (196 for N=50000)
  const int chunk = (E + NBLK - 1) / NBLK;
  const int nslab = NBC << CSH;            // total slab entries

  char* p = (char*)d_ws;
  auto carve = [&](size_t bytes) {
    char* r = p;
    p += (bytes + 255) & ~(size_t)255;
    return r;
  };
  int*   cursor = (int*)carve(256 * 4);
  int*   offs   = (int*)carve((size_t)N * 4);
  int*   cnt    = (int*)carve((size_t)N * 4);
  float* dinv   = (float*)carve((size_t)N * 4);
  int2*  bufA   = (int2*)carve((size_t)nslab * 8);
  int2*  bufB   = (int2*)carve((size_t)nslab * 8);
  u16*   h      = (u16*)carve((size_t)N * HID * 2);   // bf16 linear outputs (gathered)
  float* h1     = (float*)carve((size_t)N * HID * 4); // fp32 layer-1 activations
  float* WT1    = (float*)carve((size_t)DIN * HID * 4);
  float* WT2    = (float*)carve((size_t)HID * HID * 4);

  int gblk = (N + 63) / 64;
  int ablk = (N + 31) / 32;                   // 32 nodes per 256-thread block
  int tblk = ((DIN + HID) * 64 + 511) / 512;  // transpose tail blocks

  // ---- build: memset + fused hist/reserve/scatter + bucket sort ----
  hipMemsetAsync(cursor, 0, 256 * 4, stream);
  k_build<<<NBLK + tblk, 512, 0, stream>>>(src, dst, ew, cursor, bufA, E, NBC, chunk,
                                           W1, W2, WT1, WT2);
  k_passB<<<NBC, 512, 0, stream>>>(bufA, cursor, bufB, offs, cnt, dinv, NBC, N);
  k_norm<<<(nslab + 255) / 256, 256, 0, stream>>>(bufB, cursor, dinv, nslab);

  // ---- layer 1 ----
  k_gemm<DIN><<<gblk, 256, 0, stream>>>(x, WT1, h, N);
  k_agg<<<ablk, 256, 0, stream>>>(h, bufB, offs, cnt, dinv, b1, nullptr, h1, N, 0);
  // ---- layer 2 (reuse h buffer for h1 @ W2^T) ----
  k_gemm<HID><<<gblk, 256, 0, stream>>>(h1, WT2, h, N);
  k_agg<<<ablk, 256, 0, stream>>>(h, bufB, offs, cnt, dinv, b2, h1, out, N, 1);
}